// Round 8
// baseline (609.618 us; speedup 1.0000x reference)
//
#include <hip/hip_runtime.h>

// Problem constants
#define BATCH 64
#define CH    256
#define HW    4096
#define TOK   256
#define ITERS 30

// k2 = (dot - 1) * 1/(eps*ln2);  eps = 0.05.  E = 2^k2 = exp(-cost/eps).
constexpr float K2SCALE   = 28.853900817779268f;    // 1/(0.05*ln2)
constexpr float LOSSSCALE = -0.034657359027997264f; // -0.05*ln2  (cost = LOSSSCALE*k2)

// ws layout in floats
#define TOKP_OFF 0
#define TOKT_OFF (BATCH*CH*TOK)               // 4,194,304
#define K2_OFF   (2*BATCH*CH*TOK)             // 8,388,608
#define LOSS_OFF (K2_OFF + BATCH*TOK*TOK)     // 12,582,912
// total 12,582,976 floats = 50.3 MB

// HIP has no __exp2f fast intrinsic; use amdgcn builtins (v_exp_f32 = 2^x,
// v_log_f32 = log2 x) with ocml fallback.  (round-3 lesson)
__device__ __forceinline__ float fexp2(float x) {
#if __has_builtin(__builtin_amdgcn_exp2f)
    return __builtin_amdgcn_exp2f(x);
#else
    return exp2f(x);
#endif
}
__device__ __forceinline__ float flog2(float x) {
#if __has_builtin(__builtin_amdgcn_logf)
    return __builtin_amdgcn_logf(x);   // v_log_f32: log2(x)
#else
    return log2f(x);
#endif
}

__device__ __forceinline__ int sample_pos(int i) {
    // mimic jnp.linspace(0, 4095, 256).astype(int32): fp32 step = RN(4095/255),
    // fp32 mul, truncate.  No truncation flips (1/17 margin vs 2.5e-4 error).
    const float step = 4095.0f / 255.0f;
    return (int)((float)i * step);
}

// ---------------------------------------------------------------------------
// K1 (R6 rewrite): DENSE streaming gather.
// R5 evidence: sparse gather = 8.39M single-line requests; FETCH_SIZE = 8.39M
// x 32B exactly (gfx950 TCC fetches 32B sectors) but stuck at 1.88 TB/s and
// INVARIANT to 2x occupancy -> request-rate limited (64 distinct lines per
// wave-instr), not bytes or latency.  Fix: read the input DENSE+coalesced
// (float4/lane -> 16 line-requests/wave), stage each 16KB (b,c)-plane in LDS,
// extract the 256 sampled floats from LDS, store 1KB coalesced.  512MB moves
// at streaming BW (~6.3 TB/s proven by 1GB fill @84% peak) ~= 81us floor.
// grid 4096 = 32768 planes / 8 per block; block 256; LDS 16KB -> 8 blocks/CU.
// ---------------------------------------------------------------------------
__global__ __launch_bounds__(256) void gather_kernel(
        const float* __restrict__ pred, const float* __restrict__ targ,
        float* __restrict__ ws) {
    __shared__ float lds[HW];          // one 16KB plane
    int i   = threadIdx.x;
    int pos = sample_pos(i);
    int p0  = blockIdx.x * 8;

    for (int q = 0; q < 8; ++q) {
        int p   = p0 + q;
        int b   = p >> 9;              // 512 planes per batch (2 tensors x 256 ch)
        int rem = p & 511;
        int t   = rem >> 8;
        int c   = rem & 255;

        const float4* src4 = (const float4*)((t ? targ : pred)
                              + ((size_t)b * CH + c) * HW);
        // dense coalesced read of the whole plane: 4 float4 per thread
        float4 v0 = src4[i];
        float4 v1 = src4[i + 256];
        float4 v2 = src4[i + 512];
        float4 v3 = src4[i + 768];
        float4* l4 = (float4*)lds;
        l4[i]       = v0;
        l4[i + 256] = v1;
        l4[i + 512] = v2;
        l4[i + 768] = v3;
        __syncthreads();
        // extract my sampled element (single b32 read; conflicts negligible)
        float val = lds[pos];
        ws[(t ? TOKT_OFF : TOKP_OFF) + ((size_t)b * CH + c) * TOK + i] = val;
        __syncthreads();
    }
}

// ---------------------------------------------------------------------------
// K2 (R6): per-batch 256x256x256 fp32 GEMM -> k2 = (p.t/(|p||t|)-1)*K2SCALE.
// R5 ran grid 256 = exactly 1 block/CU = 1 wave/SIMD: zero latency hiding on
// staging.  Now 128x64 tiles -> grid 512 = 2 blocks/CU (8 waves/CU).
// Thread (tx=tid&15 rows, ty=tid>>4 cols): 8x4 acc; fragment reads conflict-
// free (A: 16 addrs span 32 banks + 4-way broadcast; B: 4 addrs broadcast).
// Norms fused in staging: A col = tid&127 const (pair tid<->tid^128 covers
// even/odd channels); B col = tid&63 const (quartet tid + {0,64,128,192}
// covers channels by cc mod 4).
// ---------------------------------------------------------------------------
__global__ __launch_bounds__(256, 2) void gemm_kernel(float* __restrict__ ws) {
    __shared__ float at[32][132];   // A: 32 ch x 128 rows (+4 pad)
    __shared__ float bt[32][68];    // B: 32 ch x 64 cols  (+4 pad)
    __shared__ float rnA[128];
    __shared__ float rnB4[3][64];
    __shared__ float rnB[64];

    int bx = blockIdx.x;
    int b = bx >> 3, tile = bx & 7;
    int i0 = (tile >> 2) * 128;     // 2 i-tiles
    int j0 = (tile & 3) * 64;       // 4 j-tiles
    int tid = threadIdx.x;
    int tx = tid & 15, ty = tid >> 4;

    const float* tp = ws + TOKP_OFF + (size_t)b * CH * TOK;
    const float* tt = ws + TOKT_OFF + (size_t)b * CH * TOK;

    float acc[8][4] = {};
    float sa = 0.0f, sb = 0.0f;

    for (int chnk = 0; chnk < 8; ++chnk) {
#pragma unroll
        for (int q = 0; q < 16; ++q) {          // A: 32x128
            int idx = q * 256 + tid;
            int cc = idx >> 7, col = idx & 127;
            float va = tp[(size_t)(chnk * 32 + cc) * TOK + i0 + col];
            at[cc][col] = va;
            sa = fmaf(va, va, sa);
        }
#pragma unroll
        for (int q = 0; q < 8; ++q) {           // B: 32x64
            int idx = q * 256 + tid;
            int cc = idx >> 6, col = idx & 63;
            float vb = tt[(size_t)(chnk * 32 + cc) * TOK + j0 + col];
            bt[cc][col] = vb;
            sb = fmaf(vb, vb, sb);
        }
        __syncthreads();
#pragma unroll
        for (int cc = 0; cc < 32; ++cc) {
            float4 a0 = *(const float4*)&at[cc][tx * 4];        // rows 4tx..+3
            float4 a1 = *(const float4*)&at[cc][64 + tx * 4];   // rows 64+4tx..+3
            float4 b0 = *(const float4*)&bt[cc][ty * 4];        // cols 4ty..+3
            float af[8] = {a0.x, a0.y, a0.z, a0.w, a1.x, a1.y, a1.z, a1.w};
            float bf[4] = {b0.x, b0.y, b0.z, b0.w};
#pragma unroll
            for (int r = 0; r < 8; ++r)
#pragma unroll
                for (int c = 0; c < 4; ++c)
                    acc[r][c] = fmaf(af[r], bf[c], acc[r][c]);
        }
        __syncthreads();
    }

    // norms: A pair-reduce, B quartet-reduce
    if (tid >= 128) rnA[tid - 128] = sa;
    if (tid >= 64)  rnB4[(tid >> 6) - 1][tid & 63] = sb;
    __syncthreads();
    if (tid < 128) {
        float fa = sa + rnA[tid];
        rnA[tid] = 1.0f / fmaxf(sqrtf(fa), 1e-12f);
    }
    if (tid < 64) {
        float fb = sb + rnB4[0][tid] + rnB4[1][tid] + rnB4[2][tid];
        rnB[tid] = 1.0f / fmaxf(sqrtf(fb), 1e-12f);
    }
    __syncthreads();

    float rpf[8], rtf[4];
#pragma unroll
    for (int r = 0; r < 8; ++r) rpf[r] = rnA[4 * tx + (r & 3) + 64 * (r >> 2)];
#pragma unroll
    for (int c = 0; c < 4; ++c) rtf[c] = rnB[4 * ty + c];

    float* K2w = ws + K2_OFF + (size_t)b * TOK * TOK;
#pragma unroll
    for (int r = 0; r < 8; ++r) {
        float out[4];
#pragma unroll
        for (int c = 0; c < 4; ++c)
            out[c] = (acc[r][c] * rpf[r] * rtf[c] - 1.0f) * K2SCALE;
        size_t row = (size_t)(i0 + 4 * tx + (r & 3) + 64 * (r >> 2)) * TOK;
        *(float4*)&K2w[row + j0 + 4 * ty] = make_float4(out[0], out[1], out[2], out[3]);
    }
}

// ---------------------------------------------------------------------------
// K3: Sinkhorn with E = 2^k2 precomputed in registers (8x8/thread).
// ZERO transcendentals in the 60-phase loop:
//   wu[i] = 2^u[i] = 2^-8 / (sum_j E[i][j]*wv[j])   (pure FMA matvec + rcp)
// grid 64 (one block per batch); block 1024 (ti=tid>>5 rows, tj=tid&31 cols).
// Reduce layout red[pos][lane], 33-float rows: all LDS ops <=2-way (free).
// ---------------------------------------------------------------------------
__global__ __launch_bounds__(1024, 1) void sinkhorn_kernel(float* __restrict__ ws) {
    __shared__ float red[256][33];
    __shared__ float wuperm[256];
    __shared__ float wvperm[256];
    __shared__ float wsum[16];

    int b = blockIdx.x;
    int tid = threadIdx.x;
    int ti = tid >> 5, tj = tid & 31;

    const float* K2r = ws + K2_OFF + (size_t)b * TOK * TOK;
    float e[8][8];
#pragma unroll
    for (int r = 0; r < 8; ++r) {
        const float4* p = (const float4*)&K2r[(size_t)(8 * ti + r) * TOK + 8 * tj];
        float4 v0 = p[0], v1 = p[1];
        e[r][0] = fexp2(v0.x); e[r][1] = fexp2(v0.y);
        e[r][2] = fexp2(v0.z); e[r][3] = fexp2(v0.w);
        e[r][4] = fexp2(v1.x); e[r][5] = fexp2(v1.y);
        e[r][6] = fexp2(v1.z); e[r][7] = fexp2(v1.w);
    }

    if (tid < 256) wvperm[tid] = 1.0f;   // wv = 2^0
    __syncthreads();

    for (int it = 0; it < ITERS; ++it) {
        // ---- u-phase: wu[i] = 2^-8 / sum_j E[i][j]*wv[j]
        float wv[8];
#pragma unroll
        for (int c = 0; c < 8; ++c) wv[c] = wvperm[tj + 32 * c];
#pragma unroll
        for (int r = 0; r < 8; ++r) {
            float s = 0.0f;
#pragma unroll
            for (int c = 0; c < 8; ++c) s = fmaf(e[r][c], wv[c], s);
            red[ti + 32 * r][tj] = s;   // bank = (ti+tj)%32 -> 2-way, free
        }
        __syncthreads();
        if (tid < 256) {
            float s = 0.0f;
#pragma unroll
            for (int q = 0; q < 32; ++q) s += red[tid][q];  // (tid+q)%32 -> 2-way
            wuperm[tid] = 0.00390625f / s;
        }
        __syncthreads();

        // ---- v-phase: wv[j] = 2^-8 / sum_i E[i][j]*wu[i]
        float wu[8];
#pragma unroll
        for (int r = 0; r < 8; ++r) wu[r] = wuperm[ti + 32 * r];  // broadcast
#pragma unroll
        for (int c = 0; c < 8; ++c) {
            float s = 0.0f;
#pragma unroll
            for (int r = 0; r < 8; ++r) s = fmaf(e[r][c], wu[r], s);
            red[tj + 32 * c][ti] = s;   // 2-way, free
        }
        __syncthreads();
        if (tid < 256) {
            float s = 0.0f;
#pragma unroll
            for (int q = 0; q < 32; ++q) s += red[tid][q];
            wvperm[tid] = 0.00390625f / s;
        }
        __syncthreads();
    }

    // ---- loss: transport = E*wu*wv; cost = LOSSSCALE*k2, k2 = log2(E)
    float wu[8], wv[8];
#pragma unroll
    for (int r = 0; r < 8; ++r) wu[r] = wuperm[ti + 32 * r];
#pragma unroll
    for (int c = 0; c < 8; ++c) wv[c] = wvperm[tj + 32 * c];

    float acc = 0.0f;
#pragma unroll
    for (int r = 0; r < 8; ++r)
#pragma unroll
        for (int c = 0; c < 8; ++c)
            acc += e[r][c] * wu[r] * wv[c] * flog2(e[r][c]);

#pragma unroll
    for (int off = 32; off >= 1; off >>= 1) acc += __shfl_xor(acc, off, 64);
    int wid = tid >> 6, lane = tid & 63;
    if (lane == 0) wsum[wid] = acc;
    __syncthreads();
    if (tid == 0) {
        float s = 0.0f;
#pragma unroll
        for (int w = 0; w < 16; ++w) s += wsum[w];
        ws[LOSS_OFF + b] = s * LOSSSCALE;
    }
}

// ---------------------------------------------------------------------------
// K4: mean over 64 batch losses
// ---------------------------------------------------------------------------
__global__ __launch_bounds__(64) void final_kernel(const float* __restrict__ ws,
                                                   float* __restrict__ out) {
    int tid = threadIdx.x;
    float v = ws[LOSS_OFF + tid];
#pragma unroll
    for (int off = 32; off >= 1; off >>= 1) v += __shfl_xor(v, off, 64);
    if (tid == 0) out[0] = v * (1.0f / 64.0f);
}

extern "C" void kernel_launch(void* const* d_in, const int* in_sizes, int n_in,
                              void* d_out, int out_size, void* d_ws, size_t ws_size,
                              hipStream_t stream) {
    const float* pred = (const float*)d_in[0];
    const float* targ = (const float*)d_in[1];
    float* ws = (float*)d_ws;
    float* out = (float*)d_out;

    hipLaunchKernelGGL(gather_kernel,   dim3(4096), dim3(256),  0, stream, pred, targ, ws);
    hipLaunchKernelGGL(gemm_kernel,     dim3(512),  dim3(256),  0, stream, ws);
    hipLaunchKernelGGL(sinkhorn_kernel, dim3(64),   dim3(1024), 0, stream, ws);
    hipLaunchKernelGGL(final_kernel,    dim3(1),    dim3(64),   0, stream, ws, out);
}